// Round 3
// baseline (954.944 us; speedup 1.0000x reference)
//
#include <hip/hip_runtime.h>
#include <hip/hip_bf16.h>

#define S_LEN 2048
#define HID 4096
#define NH 32
#define NKV 8
#define DH 128
#define QKV_N ((NH + 2 * NKV) * DH) /* 6144 */
#define SCALE_ATT 0.08838834764831845f /* 128^-0.5 */

typedef __bf16 bf16;
typedef __bf16 bf16x8 __attribute__((ext_vector_type(8)));
typedef float f32x4 __attribute__((ext_vector_type(4)));

__device__ inline f32x4 mfma16(bf16x8 a, bf16x8 b, f32x4 c) {
    return __builtin_amdgcn_mfma_f32_16x16x32_bf16(a, b, c, 0, 0, 0);
}

// load 8 contiguous elements as bf16x8 (converting if fp32 source)
__device__ inline bf16x8 load8(const float* p) {
    const float4 a = ((const float4*)p)[0];
    const float4 b = ((const float4*)p)[1];
    bf16x8 r;
    r[0] = (bf16)a.x; r[1] = (bf16)a.y; r[2] = (bf16)a.z; r[3] = (bf16)a.w;
    r[4] = (bf16)b.x; r[5] = (bf16)b.y; r[6] = (bf16)b.z; r[7] = (bf16)b.w;
    return r;
}
__device__ inline bf16x8 load8(const bf16* p) {
    return *(const bf16x8*)p;
}

// C[M x N] = A[M x K] @ B[N x K]^T   (B stored N-major, K-contiguous)
// 128x128 tile, 4 waves in 2x2, each wave 64x64 = 4x4 MFMA 16x16x32 tiles.
// lda = row stride of A (elements); allows reading Q-slot out of qkv buffer.
template <typename AT, typename OutT>
__global__ __launch_bounds__(256) void gemm_bt(const AT* __restrict__ A,
                                               const float* __restrict__ B,
                                               OutT* __restrict__ C,
                                               int K, int lda, int ldc) {
    const int tid = threadIdx.x;
    const int lane = tid & 63;
    const int w = tid >> 6;
    const int m0 = blockIdx.y * 128;
    const int n0 = blockIdx.x * 128;
    const int wm = (w >> 1) * 64;
    const int wn = (w & 1) * 64;
    const int ln = lane & 15;
    const int qo = lane >> 4;

    __shared__ bf16 As[128 * 72]; // 128 rows x 64 cols, stride 72 (pad 8)
    __shared__ bf16 Bs[128 * 72];

    f32x4 acc[4][4];
#pragma unroll
    for (int mi = 0; mi < 4; ++mi)
#pragma unroll
        for (int ni = 0; ni < 4; ++ni) acc[mi][ni] = f32x4{0.f, 0.f, 0.f, 0.f};

    for (int k0 = 0; k0 < K; k0 += 64) {
#pragma unroll
        for (int i = 0; i < 4; ++i) {
            int v = tid + i * 256;       // 1024 vec8 per tile
            int row = v >> 3;            // 8 vec8 per row of 64
            int col = (v & 7) * 8;
            *(bf16x8*)&As[row * 72 + col] = load8(&A[(size_t)(m0 + row) * lda + k0 + col]);
            *(bf16x8*)&Bs[row * 72 + col] = load8(&B[(size_t)(n0 + row) * K + k0 + col]);
        }
        __syncthreads();
#pragma unroll
        for (int kk = 0; kk < 64; kk += 32) {
            bf16x8 af[4], bfr[4];
#pragma unroll
            for (int mi = 0; mi < 4; ++mi)
                af[mi] = *(const bf16x8*)&As[(wm + mi * 16 + ln) * 72 + kk + qo * 8];
#pragma unroll
            for (int ni = 0; ni < 4; ++ni)
                bfr[ni] = *(const bf16x8*)&Bs[(wn + ni * 16 + ln) * 72 + kk + qo * 8];
#pragma unroll
            for (int mi = 0; mi < 4; ++mi)
#pragma unroll
                for (int ni = 0; ni < 4; ++ni)
                    acc[mi][ni] = mfma16(af[mi], bfr[ni], acc[mi][ni]);
        }
        __syncthreads();
    }
    // epilogue: C/D layout col=lane&15, row=(lane>>4)*4+reg
#pragma unroll
    for (int mi = 0; mi < 4; ++mi)
#pragma unroll
        for (int ni = 0; ni < 4; ++ni)
#pragma unroll
            for (int r = 0; r < 4; ++r) {
                int row = m0 + wm + mi * 16 + qo * 4 + r;
                int col = n0 + wn + ni * 16 + ln;
                C[(size_t)row * ldc + col] = (OutT)acc[mi][ni][r];
            }
}

// RoPE in-place on bf16 qkv buffer: q heads 0..31 at col h*128, k heads at 4096+kvh*128
__global__ __launch_bounds__(256) void rope_kernel(bf16* __restrict__ qkv,
                                                   const int* __restrict__ positions) {
    int idx = blockIdx.x * 256 + threadIdx.x;
    const int total = S_LEN * (NH + NKV) * 64;
    if (idx >= total) return;
    int d = idx & 63;
    int t = idx >> 6;
    int head = t % (NH + NKV);
    int s = t / (NH + NKV);
    size_t base = (size_t)s * QKV_N + (head < NH ? head * DH : NH * DH + (head - NH) * DH);
    float x1 = (float)qkv[base + d];
    float x2 = (float)qkv[base + d + 64];
    float pos = (float)positions[s];
    // inv_freq = 1e6^(-d/64) = exp(-d * ln(1e6)/64)
    float inv = expf(-0.21586735246819178f * (float)d);
    float ang = pos * inv;
    float c = cosf(ang);
    float sn = sinf(ang);
    qkv[base + d] = (bf16)(x1 * c - x2 * sn);
    qkv[base + d + 64] = (bf16)(x2 * c + x1 * sn);
}

// Flash attention: block = (q-tile of 64 rows, head). 4 waves x 16 q-rows.
// KV tiles of 64 keys. Online softmax. GQA: kv head = hq/4.
// Output O is written IN-PLACE into the Q slot of qkv (rows q0..q0+63, head hq).
// Safe: only this block ever reads that region (staged to LDS before K-loop);
// K/V columns >= 4096 are never written.
__global__ __launch_bounds__(256) void attn_kernel(bf16* __restrict__ qkv) {
    const int tid = threadIdx.x;
    const int lane = tid & 63;
    const int w = tid >> 6;
    const int ln = lane & 15;
    const int qo = lane >> 4;
    const int qtile = blockIdx.x;
    const int hq = blockIdx.y;
    const int kvh = hq >> 2;
    const int q0 = qtile * 64;

    __shared__ bf16 Qs[64 * 136];
    __shared__ bf16 Ks[64 * 136];
    __shared__ bf16 Vt[128 * 72]; // transposed: [d][key]
    __shared__ bf16 Ps[4 * 16 * 72];

    // stage Q tile (64 x 128)
#pragma unroll
    for (int i = 0; i < 4; ++i) {
        int v = tid + i * 256;
        int row = v >> 4;
        int col = (v & 15) * 8;
        *(bf16x8*)&Qs[row * 136 + col] =
            *(const bf16x8*)&qkv[(size_t)(q0 + row) * QKV_N + hq * DH + col];
    }
    __syncthreads();

    bf16x8 aq[4]; // Q fragments: A[m=ln][k=qo*8+j], 4 K-steps of 32 over D=128
#pragma unroll
    for (int ko = 0; ko < 4; ++ko)
        aq[ko] = *(const bf16x8*)&Qs[(w * 16 + ln) * 136 + ko * 32 + qo * 8];

    f32x4 acc[8]; // O accumulator: 16 rows x 128 d = 8 n-tiles
#pragma unroll
    for (int n = 0; n < 8; ++n) acc[n] = f32x4{0.f, 0.f, 0.f, 0.f};
    float m_r[4], l_r[4];
#pragma unroll
    for (int r = 0; r < 4; ++r) { m_r[r] = -1e30f; l_r[r] = 0.f; }

    bf16* Ps_w = &Ps[w * 16 * 72];

    for (int kt = 0; kt <= qtile; ++kt) {
        const int k0 = kt * 64;
        // stage K (row-major) and V (transposed)
#pragma unroll
        for (int i = 0; i < 4; ++i) {
            int v = tid + i * 256;
            int row = v >> 4;
            int col = (v & 15) * 8;
            *(bf16x8*)&Ks[row * 136 + col] =
                *(const bf16x8*)&qkv[(size_t)(k0 + row) * QKV_N + NH * DH + kvh * DH + col];
            bf16x8 vv =
                *(const bf16x8*)&qkv[(size_t)(k0 + row) * QKV_N + (NH + NKV) * DH + kvh * DH + col];
#pragma unroll
            for (int j = 0; j < 8; ++j) Vt[(col + j) * 72 + row] = vv[j];
        }
        __syncthreads();

        // S = Q K^T (16 q-rows x 64 keys per wave)
        float p[4][4]; // [ni][reg]
#pragma unroll
        for (int ni = 0; ni < 4; ++ni) {
            f32x4 sacc = f32x4{0.f, 0.f, 0.f, 0.f};
#pragma unroll
            for (int ko = 0; ko < 4; ++ko) {
                bf16x8 bk = *(const bf16x8*)&Ks[(ni * 16 + ln) * 136 + ko * 32 + qo * 8];
                sacc = mfma16(aq[ko], bk, sacc);
            }
#pragma unroll
            for (int r = 0; r < 4; ++r) {
                float val = sacc[r] * SCALE_ATT;
                int qrow = q0 + w * 16 + qo * 4 + r;
                int kcol = k0 + ni * 16 + ln;
                if (kcol > qrow) val = -1e30f; // causal
                p[ni][r] = val;
            }
        }
        // online softmax (rows live across lanes ln=0..15 with same qo)
        float alpha[4];
#pragma unroll
        for (int r = 0; r < 4; ++r) {
            float mx = fmaxf(fmaxf(p[0][r], p[1][r]), fmaxf(p[2][r], p[3][r]));
#pragma unroll
            for (int off = 1; off < 16; off <<= 1)
                mx = fmaxf(mx, __shfl_xor(mx, off, 64));
            float mnew = fmaxf(m_r[r], mx);
            alpha[r] = __expf(m_r[r] - mnew);
            float rs = 0.f;
#pragma unroll
            for (int ni = 0; ni < 4; ++ni) {
                float e = __expf(p[ni][r] - mnew);
                p[ni][r] = e;
                rs += e;
            }
#pragma unroll
            for (int off = 1; off < 16; off <<= 1) rs += __shfl_xor(rs, off, 64);
            l_r[r] = l_r[r] * alpha[r] + rs;
            m_r[r] = mnew;
        }
#pragma unroll
        for (int n = 0; n < 8; ++n)
#pragma unroll
            for (int r = 0; r < 4; ++r) acc[n][r] *= alpha[r];
        // P: C-layout -> LDS -> A-layout (per-wave region)
#pragma unroll
        for (int ni = 0; ni < 4; ++ni)
#pragma unroll
            for (int r = 0; r < 4; ++r)
                Ps_w[(qo * 4 + r) * 72 + ni * 16 + ln] = (bf16)p[ni][r];
        __syncthreads();
        // O += P V  (K-dim = 64 keys = 2 MFMA k-steps)
#pragma unroll
        for (int ko2 = 0; ko2 < 2; ++ko2) {
            bf16x8 pf = *(const bf16x8*)&Ps_w[ln * 72 + ko2 * 32 + qo * 8];
#pragma unroll
            for (int n = 0; n < 8; ++n) {
                bf16x8 vf = *(const bf16x8*)&Vt[(n * 16 + ln) * 72 + ko2 * 32 + qo * 8];
                acc[n] = mfma16(pf, vf, acc[n]);
            }
        }
        __syncthreads();
    }
    // epilogue: O / l -> Q slot of qkv (in-place)
#pragma unroll
    for (int r = 0; r < 4; ++r) {
        float invl = 1.f / l_r[r];
        int qrow = q0 + w * 16 + qo * 4 + r;
#pragma unroll
        for (int n = 0; n < 8; ++n)
            qkv[(size_t)qrow * QKV_N + hq * DH + n * 16 + ln] = (bf16)(acc[n][r] * invl);
    }
}

extern "C" void kernel_launch(void* const* d_in, const int* in_sizes, int n_in,
                              void* d_out, int out_size, void* d_ws, size_t ws_size,
                              hipStream_t stream) {
    const int* positions = (const int*)d_in[0];
    const float* hidden = (const float*)d_in[1];
    const float* w_qkv = (const float*)d_in[2];
    const float* w_o = (const float*)d_in[3];
    float* out = (float*)d_out;

    // Workspace: qkv only (S x 6144 bf16 = 25.2 MB). Attention output reuses
    // the Q slot in-place, so no second buffer.
    const size_t need = (size_t)S_LEN * QKV_N * sizeof(bf16);
    if (ws_size < need) return; // diagnostic: zeros out -> clean absmax failure, not a crash
    bf16* qkv = (bf16*)d_ws;

    // 1) qkv = hidden @ w_qkv^T   (M=2048, N=6144, K=4096)
    gemm_bt<<<dim3(QKV_N / 128, S_LEN / 128), 256, 0, stream>>>(hidden, w_qkv, qkv, HID, HID, QKV_N);
    // 2) RoPE in-place on q and k
    const int total = S_LEN * (NH + NKV) * 64;
    rope_kernel<<<(total + 255) / 256, 256, 0, stream>>>(qkv, positions);
    // 3) causal GQA flash attention, O written into Q slot of qkv
    attn_kernel<<<dim3(S_LEN / 64, NH), 256, 0, stream>>>(qkv);
    // 4) out = O @ w_o^T  (M=2048, N=4096, K=4096), A = Q-slot of qkv (lda=6144)
    gemm_bt<<<dim3(HID / 128, S_LEN / 128), 256, 0, stream>>>(qkv, w_o, out, HID, QKV_N, HID);
}

// Round 4
// 754.241 us; speedup vs baseline: 1.2661x; 1.2661x over previous
//
#include <hip/hip_runtime.h>
#include <hip/hip_bf16.h>

#define S_LEN 2048
#define HID 4096
#define NH 32
#define NKV 8
#define DH 128
#define QKV_N ((NH + 2 * NKV) * DH) /* 6144 */
#define SCALE_ATT 0.08838834764831845f /* 128^-0.5 */

typedef __bf16 bf16;
typedef __bf16 bf16x8 __attribute__((ext_vector_type(8)));
typedef float f32x4 __attribute__((ext_vector_type(4)));

__device__ inline f32x4 mfma16(bf16x8 a, bf16x8 b, f32x4 c) {
    return __builtin_amdgcn_mfma_f32_16x16x32_bf16(a, b, c, 0, 0, 0);
}

// load 8 contiguous elements as bf16x8 (converting if fp32 source)
__device__ inline bf16x8 load8(const float* p) {
    const float4 a = ((const float4*)p)[0];
    const float4 b = ((const float4*)p)[1];
    bf16x8 r;
    r[0] = (bf16)a.x; r[1] = (bf16)a.y; r[2] = (bf16)a.z; r[3] = (bf16)a.w;
    r[4] = (bf16)b.x; r[5] = (bf16)b.y; r[6] = (bf16)b.z; r[7] = (bf16)b.w;
    return r;
}
__device__ inline bf16x8 load8(const bf16* p) {
    return *(const bf16x8*)p;
}

// C[M x N] = A[M x K] @ B[N x K]^T   (B stored N-major, K-contiguous)
// 128x128 tile, 4 waves in 2x2, each wave 64x64 = 4x4 MFMA 16x16x32 tiles.
template <typename AT, typename OutT>
__global__ __launch_bounds__(256) void gemm_bt(const AT* __restrict__ A,
                                               const float* __restrict__ B,
                                               OutT* __restrict__ C,
                                               int K, int lda, int ldc) {
    const int tid = threadIdx.x;
    const int lane = tid & 63;
    const int w = tid >> 6;
    const int m0 = blockIdx.y * 128;
    const int n0 = blockIdx.x * 128;
    const int wm = (w >> 1) * 64;
    const int wn = (w & 1) * 64;
    const int ln = lane & 15;
    const int qo = lane >> 4;

    __shared__ bf16 As[128 * 72]; // 128 rows x 64 cols, stride 72 (pad 8)
    __shared__ bf16 Bs[128 * 72];

    f32x4 acc[4][4];
#pragma unroll
    for (int mi = 0; mi < 4; ++mi)
#pragma unroll
        for (int ni = 0; ni < 4; ++ni) acc[mi][ni] = f32x4{0.f, 0.f, 0.f, 0.f};

    for (int k0 = 0; k0 < K; k0 += 64) {
#pragma unroll
        for (int i = 0; i < 4; ++i) {
            int v = tid + i * 256;       // 1024 vec8 per tile
            int row = v >> 3;            // 8 vec8 per row of 64
            int col = (v & 7) * 8;
            *(bf16x8*)&As[row * 72 + col] = load8(&A[(size_t)(m0 + row) * lda + k0 + col]);
            *(bf16x8*)&Bs[row * 72 + col] = load8(&B[(size_t)(n0 + row) * K + k0 + col]);
        }
        __syncthreads();
#pragma unroll
        for (int kk = 0; kk < 64; kk += 32) {
            bf16x8 af[4], bfr[4];
#pragma unroll
            for (int mi = 0; mi < 4; ++mi)
                af[mi] = *(const bf16x8*)&As[(wm + mi * 16 + ln) * 72 + kk + qo * 8];
#pragma unroll
            for (int ni = 0; ni < 4; ++ni)
                bfr[ni] = *(const bf16x8*)&Bs[(wn + ni * 16 + ln) * 72 + kk + qo * 8];
#pragma unroll
            for (int mi = 0; mi < 4; ++mi)
#pragma unroll
                for (int ni = 0; ni < 4; ++ni)
                    acc[mi][ni] = mfma16(af[mi], bfr[ni], acc[mi][ni]);
        }
        __syncthreads();
    }
    // epilogue: C/D layout col=lane&15, row=(lane>>4)*4+reg
#pragma unroll
    for (int mi = 0; mi < 4; ++mi)
#pragma unroll
        for (int ni = 0; ni < 4; ++ni)
#pragma unroll
            for (int r = 0; r < 4; ++r) {
                int row = m0 + wm + mi * 16 + qo * 4 + r;
                int col = n0 + wn + ni * 16 + ln;
                C[(size_t)row * ldc + col] = (OutT)acc[mi][ni][r];
            }
}

// RoPE in-place on bf16 qkv buffer
__global__ __launch_bounds__(256) void rope_kernel(bf16* __restrict__ qkv,
                                                   const int* __restrict__ positions) {
    int idx = blockIdx.x * 256 + threadIdx.x;
    const int total = S_LEN * (NH + NKV) * 64;
    if (idx >= total) return;
    int d = idx & 63;
    int t = idx >> 6;
    int head = t % (NH + NKV);
    int s = t / (NH + NKV);
    size_t base = (size_t)s * QKV_N + (head < NH ? head * DH : NH * DH + (head - NH) * DH);
    float x1 = (float)qkv[base + d];
    float x2 = (float)qkv[base + d + 64];
    float pos = (float)positions[s];
    float inv = expf(-0.21586735246819178f * (float)d); // 1e6^(-d/64)
    float ang = pos * inv;
    float c = cosf(ang);
    float sn = sinf(ang);
    qkv[base + d] = (bf16)(x1 * c - x2 * sn);
    qkv[base + d + 64] = (bf16)(x2 * c + x1 * sn);
}

// Pre-transpose V into vt_g[kvh][d][s] so attention can stage V^T tiles with
// conflict-free coalesced b128 LDS writes (the in-kernel scalar transpose was
// a 32-way bank conflict: 7.4e7 conflict cycles measured in round 3).
__global__ __launch_bounds__(256) void vtrans_kernel(const bf16* __restrict__ qkv,
                                                     bf16* __restrict__ vt_g) {
    const int tid = threadIdx.x;
    const int s0 = blockIdx.x * 64;
    const int kvh = blockIdx.y;
    __shared__ bf16 Ls[64 * 136];
#pragma unroll
    for (int i = 0; i < 4; ++i) {
        int v = tid + i * 256;
        int row = v >> 4;          // s offset 0..63
        int col = (v & 15) * 8;    // d offset 0..120
        *(bf16x8*)&Ls[row * 136 + col] =
            *(const bf16x8*)&qkv[(size_t)(s0 + row) * QKV_N + (NH + NKV) * DH + kvh * DH + col];
    }
    __syncthreads();
#pragma unroll
    for (int i = 0; i < 4; ++i) {
        int u = tid + i * 256;
        int d = u >> 3;            // 0..127
        int sg = (u & 7) * 8;      // 0..56
        bf16x8 r;
#pragma unroll
        for (int j = 0; j < 8; ++j) r[j] = Ls[(sg + j) * 136 + d];
        *(bf16x8*)&vt_g[((size_t)kvh * DH + d) * S_LEN + s0 + sg] = r;
    }
}

// Flash attention, vt_g variant. Block = (q-tile 64 rows, q-head).
// LDS 53.2 KB -> 3 blocks/CU (was 62.4 KB -> 2). Ps aliases dead Qs.
// qtile reversed (heavy blocks first) to kill the triangular-workload tail.
// O written in-place into the Q slot of qkv.
__global__ __launch_bounds__(256) void attn_kernel(bf16* __restrict__ qkv,
                                                   const bf16* __restrict__ vt_g) {
    const int tid = threadIdx.x;
    const int lane = tid & 63;
    const int w = tid >> 6;
    const int ln = lane & 15;
    const int qo = lane >> 4;
    const int qtile = (int)gridDim.x - 1 - (int)blockIdx.x; // heavy first
    const int hq = blockIdx.y;
    const int kvh = hq >> 2;
    const int q0 = qtile * 64;

    __shared__ __align__(16) char smem_raw[2 * 17408 + 18432]; // 53248 B
    bf16* Qs = (bf16*)smem_raw;              // 64 x 136 (dead after frag load)
    bf16* Ps = (bf16*)smem_raw;              // aliases Qs; 4 waves x 16 x 72
    bf16* Ks = (bf16*)(smem_raw + 17408);    // 64 x 136
    bf16* Vt = (bf16*)(smem_raw + 2 * 17408); // 128 x 72  [d][key]

    // stage Q tile (64 x 128)
#pragma unroll
    for (int i = 0; i < 4; ++i) {
        int v = tid + i * 256;
        int row = v >> 4;
        int col = (v & 15) * 8;
        *(bf16x8*)&Qs[row * 136 + col] =
            *(const bf16x8*)&qkv[(size_t)(q0 + row) * QKV_N + hq * DH + col];
    }
    __syncthreads();

    bf16x8 aq[4]; // Q fragments: A[m=ln][k=qo*8+j], 4 K-steps of 32 over D=128
#pragma unroll
    for (int ko = 0; ko < 4; ++ko)
        aq[ko] = *(const bf16x8*)&Qs[(w * 16 + ln) * 136 + ko * 32 + qo * 8];

    f32x4 acc[8];
#pragma unroll
    for (int n = 0; n < 8; ++n) acc[n] = f32x4{0.f, 0.f, 0.f, 0.f};
    float m_r[4], l_r[4];
#pragma unroll
    for (int r = 0; r < 4; ++r) { m_r[r] = -1e30f; l_r[r] = 0.f; }

    bf16* Ps_w = &Ps[w * 16 * 72];
    const bf16* vsrc = vt_g + (size_t)kvh * DH * S_LEN;

    for (int kt = 0; kt <= qtile; ++kt) {
        const int k0 = kt * 64;
        // stage K row-major (conflict-free b128) ...
#pragma unroll
        for (int i = 0; i < 4; ++i) {
            int v = tid + i * 256;
            int row = v >> 4;
            int col = (v & 15) * 8;
            *(bf16x8*)&Ks[row * 136 + col] =
                *(const bf16x8*)&qkv[(size_t)(k0 + row) * QKV_N + NH * DH + kvh * DH + col];
        }
        // ... and V^T tile straight from vt_g (conflict-free b128 writes)
#pragma unroll
        for (int i = 0; i < 4; ++i) {
            int u = tid + i * 256;
            int d = u >> 3;           // 0..127
            int kc = (u & 7) * 8;     // 0..56
            *(bf16x8*)&Vt[d * 72 + kc] =
                *(const bf16x8*)&vsrc[(size_t)d * S_LEN + k0 + kc];
        }
        __syncthreads();

        // S = Q K^T (16 q-rows x 64 keys per wave)
        float p[4][4];
#pragma unroll
        for (int ni = 0; ni < 4; ++ni) {
            f32x4 sacc = f32x4{0.f, 0.f, 0.f, 0.f};
#pragma unroll
            for (int ko = 0; ko < 4; ++ko) {
                bf16x8 bk = *(const bf16x8*)&Ks[(ni * 16 + ln) * 136 + ko * 32 + qo * 8];
                sacc = mfma16(aq[ko], bk, sacc);
            }
#pragma unroll
            for (int r = 0; r < 4; ++r) {
                float val = sacc[r] * SCALE_ATT;
                int qrow = q0 + w * 16 + qo * 4 + r;
                int kcol = k0 + ni * 16 + ln;
                if (kcol > qrow) val = -1e30f; // causal
                p[ni][r] = val;
            }
        }
        // online softmax
        float alpha[4];
#pragma unroll
        for (int r = 0; r < 4; ++r) {
            float mx = fmaxf(fmaxf(p[0][r], p[1][r]), fmaxf(p[2][r], p[3][r]));
#pragma unroll
            for (int off = 1; off < 16; off <<= 1)
                mx = fmaxf(mx, __shfl_xor(mx, off, 64));
            float mnew = fmaxf(m_r[r], mx);
            alpha[r] = __expf(m_r[r] - mnew);
            float rs = 0.f;
#pragma unroll
            for (int ni = 0; ni < 4; ++ni) {
                float e = __expf(p[ni][r] - mnew);
                p[ni][r] = e;
                rs += e;
            }
#pragma unroll
            for (int off = 1; off < 16; off <<= 1) rs += __shfl_xor(rs, off, 64);
            l_r[r] = l_r[r] * alpha[r] + rs;
            m_r[r] = mnew;
        }
#pragma unroll
        for (int n = 0; n < 8; ++n)
#pragma unroll
            for (int r = 0; r < 4; ++r) acc[n][r] *= alpha[r];
        // P: C-layout -> LDS (aliases Qs) -> A-layout
#pragma unroll
        for (int ni = 0; ni < 4; ++ni)
#pragma unroll
            for (int r = 0; r < 4; ++r)
                Ps_w[(qo * 4 + r) * 72 + ni * 16 + ln] = (bf16)p[ni][r];
        __syncthreads();
        // O += P V
#pragma unroll
        for (int ko2 = 0; ko2 < 2; ++ko2) {
            bf16x8 pf = *(const bf16x8*)&Ps_w[ln * 72 + ko2 * 32 + qo * 8];
#pragma unroll
            for (int n = 0; n < 8; ++n) {
                bf16x8 vf = *(const bf16x8*)&Vt[(n * 16 + ln) * 72 + ko2 * 32 + qo * 8];
                acc[n] = mfma16(pf, vf, acc[n]);
            }
        }
        __syncthreads();
    }
    // epilogue: O / l -> Q slot of qkv (in-place)
#pragma unroll
    for (int r = 0; r < 4; ++r) {
        float invl = 1.f / l_r[r];
        int qrow = q0 + w * 16 + qo * 4 + r;
#pragma unroll
        for (int n = 0; n < 8; ++n)
            qkv[(size_t)qrow * QKV_N + hq * DH + n * 16 + ln] = (bf16)(acc[n][r] * invl);
    }
}

// Legacy attention (in-LDS V transpose, 62.4 KB LDS) — fallback when ws_size
// can't fit vt_g. Deterministic branch on ws_size => graph-capture safe.
__global__ __launch_bounds__(256) void attn_kernel_legacy(bf16* __restrict__ qkv) {
    const int tid = threadIdx.x;
    const int lane = tid & 63;
    const int w = tid >> 6;
    const int ln = lane & 15;
    const int qo = lane >> 4;
    const int qtile = (int)gridDim.x - 1 - (int)blockIdx.x;
    const int hq = blockIdx.y;
    const int kvh = hq >> 2;
    const int q0 = qtile * 64;

    __shared__ bf16 Qs[64 * 136];
    __shared__ bf16 Ks[64 * 136];
    __shared__ bf16 Vt[128 * 72];
    __shared__ bf16 Ps[4 * 16 * 72];

#pragma unroll
    for (int i = 0; i < 4; ++i) {
        int v = tid + i * 256;
        int row = v >> 4;
        int col = (v & 15) * 8;
        *(bf16x8*)&Qs[row * 136 + col] =
            *(const bf16x8*)&qkv[(size_t)(q0 + row) * QKV_N + hq * DH + col];
    }
    __syncthreads();
    bf16x8 aq[4];
#pragma unroll
    for (int ko = 0; ko < 4; ++ko)
        aq[ko] = *(const bf16x8*)&Qs[(w * 16 + ln) * 136 + ko * 32 + qo * 8];
    f32x4 acc[8];
#pragma unroll
    for (int n = 0; n < 8; ++n) acc[n] = f32x4{0.f, 0.f, 0.f, 0.f};
    float m_r[4], l_r[4];
#pragma unroll
    for (int r = 0; r < 4; ++r) { m_r[r] = -1e30f; l_r[r] = 0.f; }
    bf16* Ps_w = &Ps[w * 16 * 72];

    for (int kt = 0; kt <= qtile; ++kt) {
        const int k0 = kt * 64;
#pragma unroll
        for (int i = 0; i < 4; ++i) {
            int v = tid + i * 256;
            int row = v >> 4;
            int col = (v & 15) * 8;
            *(bf16x8*)&Ks[row * 136 + col] =
                *(const bf16x8*)&qkv[(size_t)(k0 + row) * QKV_N + NH * DH + kvh * DH + col];
            bf16x8 vv =
                *(const bf16x8*)&qkv[(size_t)(k0 + row) * QKV_N + (NH + NKV) * DH + kvh * DH + col];
#pragma unroll
            for (int j = 0; j < 8; ++j) Vt[(col + j) * 72 + row] = vv[j];
        }
        __syncthreads();
        float p[4][4];
#pragma unroll
        for (int ni = 0; ni < 4; ++ni) {
            f32x4 sacc = f32x4{0.f, 0.f, 0.f, 0.f};
#pragma unroll
            for (int ko = 0; ko < 4; ++ko) {
                bf16x8 bk = *(const bf16x8*)&Ks[(ni * 16 + ln) * 136 + ko * 32 + qo * 8];
                sacc = mfma16(aq[ko], bk, sacc);
            }
#pragma unroll
            for (int r = 0; r < 4; ++r) {
                float val = sacc[r] * SCALE_ATT;
                int qrow = q0 + w * 16 + qo * 4 + r;
                int kcol = k0 + ni * 16 + ln;
                if (kcol > qrow) val = -1e30f;
                p[ni][r] = val;
            }
        }
        float alpha[4];
#pragma unroll
        for (int r = 0; r < 4; ++r) {
            float mx = fmaxf(fmaxf(p[0][r], p[1][r]), fmaxf(p[2][r], p[3][r]));
#pragma unroll
            for (int off = 1; off < 16; off <<= 1)
                mx = fmaxf(mx, __shfl_xor(mx, off, 64));
            float mnew = fmaxf(m_r[r], mx);
            alpha[r] = __expf(m_r[r] - mnew);
            float rs = 0.f;
#pragma unroll
            for (int ni = 0; ni < 4; ++ni) {
                float e = __expf(p[ni][r] - mnew);
                p[ni][r] = e;
                rs += e;
            }
#pragma unroll
            for (int off = 1; off < 16; off <<= 1) rs += __shfl_xor(rs, off, 64);
            l_r[r] = l_r[r] * alpha[r] + rs;
            m_r[r] = mnew;
        }
#pragma unroll
        for (int n = 0; n < 8; ++n)
#pragma unroll
            for (int r = 0; r < 4; ++r) acc[n][r] *= alpha[r];
#pragma unroll
        for (int ni = 0; ni < 4; ++ni)
#pragma unroll
            for (int r = 0; r < 4; ++r)
                Ps_w[(qo * 4 + r) * 72 + ni * 16 + ln] = (bf16)p[ni][r];
        __syncthreads();
#pragma unroll
        for (int ko2 = 0; ko2 < 2; ++ko2) {
            bf16x8 pf = *(const bf16x8*)&Ps_w[ln * 72 + ko2 * 32 + qo * 8];
#pragma unroll
            for (int n = 0; n < 8; ++n) {
                bf16x8 vf = *(const bf16x8*)&Vt[(n * 16 + ln) * 72 + ko2 * 32 + qo * 8];
                acc[n] = mfma16(pf, vf, acc[n]);
            }
        }
        __syncthreads();
    }
#pragma unroll
    for (int r = 0; r < 4; ++r) {
        float invl = 1.f / l_r[r];
        int qrow = q0 + w * 16 + qo * 4 + r;
#pragma unroll
        for (int n = 0; n < 8; ++n)
            qkv[(size_t)qrow * QKV_N + hq * DH + n * 16 + ln] = (bf16)(acc[n][r] * invl);
    }
}

extern "C" void kernel_launch(void* const* d_in, const int* in_sizes, int n_in,
                              void* d_out, int out_size, void* d_ws, size_t ws_size,
                              hipStream_t stream) {
    const int* positions = (const int*)d_in[0];
    const float* hidden = (const float*)d_in[1];
    const float* w_qkv = (const float*)d_in[2];
    const float* w_o = (const float*)d_in[3];
    float* out = (float*)d_out;

    const size_t need_qkv = (size_t)S_LEN * QKV_N * sizeof(bf16);      // 25.2 MB
    const size_t need_vt = (size_t)NKV * DH * S_LEN * sizeof(bf16);    // 4.2 MB
    if (ws_size < need_qkv) return; // clean absmax failure, not a crash
    bf16* qkv = (bf16*)d_ws;
    const bool has_vt = ws_size >= need_qkv + need_vt;
    bf16* vt_g = qkv + (size_t)S_LEN * QKV_N;

    // 1) qkv = hidden @ w_qkv^T
    gemm_bt<<<dim3(QKV_N / 128, S_LEN / 128), 256, 0, stream>>>(hidden, w_qkv, qkv, HID, HID, QKV_N);
    // 2) RoPE in-place on q and k
    const int total = S_LEN * (NH + NKV) * 64;
    rope_kernel<<<(total + 255) / 256, 256, 0, stream>>>(qkv, positions);
    // 3) attention (O -> Q slot of qkv)
    if (has_vt) {
        vtrans_kernel<<<dim3(S_LEN / 64, NKV), 256, 0, stream>>>(qkv, vt_g);
        attn_kernel<<<dim3(S_LEN / 64, NH), 256, 0, stream>>>(qkv, vt_g);
    } else {
        attn_kernel_legacy<<<dim3(S_LEN / 64, NH), 256, 0, stream>>>(qkv);
    }
    // 4) out = O @ w_o^T  (A = Q-slot of qkv, lda = 6144)
    gemm_bt<<<dim3(HID / 128, S_LEN / 128), 256, 0, stream>>>(qkv, w_o, out, HID, QKV_N, HID);
}

// Round 5
// 601.325 us; speedup vs baseline: 1.5881x; 1.2543x over previous
//
#include <hip/hip_runtime.h>
#include <hip/hip_bf16.h>

#define S_LEN 2048
#define HID 4096
#define NH 32
#define NKV 8
#define DH 128
#define QKV_N ((NH + 2 * NKV) * DH) /* 6144 */
#define SCALE_ATT 0.08838834764831845f /* 128^-0.5 */

typedef __bf16 bf16;
typedef __bf16 bf16x8 __attribute__((ext_vector_type(8)));
typedef float f32x4 __attribute__((ext_vector_type(4)));

__device__ inline f32x4 mfma16(bf16x8 a, bf16x8 b, f32x4 c) {
    return __builtin_amdgcn_mfma_f32_16x16x32_bf16(a, b, c, 0, 0, 0);
}

__device__ inline bf16x8 load8(const float* p) {
    const float4 a = ((const float4*)p)[0];
    const float4 b = ((const float4*)p)[1];
    bf16x8 r;
    r[0] = (bf16)a.x; r[1] = (bf16)a.y; r[2] = (bf16)a.z; r[3] = (bf16)a.w;
    r[4] = (bf16)b.x; r[5] = (bf16)b.y; r[6] = (bf16)b.z; r[7] = (bf16)b.w;
    return r;
}
__device__ inline bf16x8 load8(const bf16* p) { return *(const bf16x8*)p; }

// direct global->LDS DMA, 16 bytes/lane. LDS dest is wave-uniform base + lane*16.
__device__ inline void load_lds16(const bf16* g, bf16* lds_base) {
    __builtin_amdgcn_global_load_lds(
        (const __attribute__((address_space(1))) void*)g,
        (__attribute__((address_space(3))) void*)lds_base, 16, 0, 0);
}

// fp32 -> bf16 bulk convert (8 elts/thread)
__global__ __launch_bounds__(256) void cvt_kernel(const float* __restrict__ src,
                                                  bf16* __restrict__ dst, int n8) {
    int i = blockIdx.x * 256 + threadIdx.x;
    if (i >= n8) return;
    *(bf16x8*)&dst[(size_t)i * 8] = load8(&src[(size_t)i * 8]);
}

// ---------------- swizzled bf16 GEMM (global_load_lds path) ----------------
// C[M x N] = A[M x K] @ B[N x K]^T, both bf16. 128x128 tile, BK=64, 4 waves.
// LDS is unpadded [128][64] with XOR-swizzle: slot (r,c) holds global chunk
// c^(r&7) (chunks = 8 bf16 = 16 B). Staging lanes permute source chunks within
// each 128-B row (coalescing kept); fragment reads XOR with ln&7 -> all 32
// banks covered at 2 lanes/bank (free, m136).
template <typename OutT>
__global__ __launch_bounds__(256) void gemm_bt_swz(const bf16* __restrict__ A,
                                                   const bf16* __restrict__ B,
                                                   OutT* __restrict__ C,
                                                   int K, int lda, int ldc) {
    const int tid = threadIdx.x;
    const int lane = tid & 63;
    const int w = tid >> 6;
    const int m0 = blockIdx.y * 128;
    const int n0 = blockIdx.x * 128;
    const int wm = (w >> 1) * 64;
    const int wn = (w & 1) * 64;
    const int ln = lane & 15;
    const int qo = lane >> 4;

    __shared__ bf16 As[128 * 64]; // 16 KB, no pad (global_load_lds requirement)
    __shared__ bf16 Bs[128 * 64];

    const int rseg = lane >> 3;                       // row within 8-row segment
    const int gc = (lane & 7) ^ (rseg & 7);           // swizzled source chunk

    f32x4 acc[4][4];
#pragma unroll
    for (int mi = 0; mi < 4; ++mi)
#pragma unroll
        for (int ni = 0; ni < 4; ++ni) acc[mi][ni] = f32x4{0.f, 0.f, 0.f, 0.f};

    for (int k0 = 0; k0 < K; k0 += 64) {
#pragma unroll
        for (int j = 0; j < 4; ++j) {
            const int seg = w * 4 + j;                // 16 segs of 8 rows
            const int r = seg * 8 + rseg;
            load_lds16(&A[(size_t)(m0 + r) * lda + k0 + gc * 8], &As[seg * 512]);
            load_lds16(&B[(size_t)(n0 + r) * K + k0 + gc * 8], &Bs[seg * 512]);
        }
        __syncthreads();
#pragma unroll
        for (int kk = 0; kk < 2; ++kk) {
            bf16x8 af[4], bfr[4];
#pragma unroll
            for (int mi = 0; mi < 4; ++mi) {
                const int m = wm + mi * 16 + ln;
                const int sc = (kk * 4 + qo) ^ (ln & 7);
                af[mi] = *(const bf16x8*)&As[m * 64 + sc * 8];
            }
#pragma unroll
            for (int ni = 0; ni < 4; ++ni) {
                const int n = wn + ni * 16 + ln;
                const int sc = (kk * 4 + qo) ^ (ln & 7);
                bfr[ni] = *(const bf16x8*)&Bs[n * 64 + sc * 8];
            }
#pragma unroll
            for (int mi = 0; mi < 4; ++mi)
#pragma unroll
                for (int ni = 0; ni < 4; ++ni)
                    acc[mi][ni] = mfma16(af[mi], bfr[ni], acc[mi][ni]);
        }
        __syncthreads();
    }
#pragma unroll
    for (int mi = 0; mi < 4; ++mi)
#pragma unroll
        for (int ni = 0; ni < 4; ++ni)
#pragma unroll
            for (int r = 0; r < 4; ++r) {
                int row = m0 + wm + mi * 16 + qo * 4 + r;
                int col = n0 + wn + ni * 16 + ln;
                C[(size_t)row * ldc + col] = (OutT)acc[mi][ni][r];
            }
}

// ---------------- fallback fp32-staging GEMM (round-4 proven) ----------------
template <typename AT, typename OutT>
__global__ __launch_bounds__(256) void gemm_bt(const AT* __restrict__ A,
                                               const float* __restrict__ B,
                                               OutT* __restrict__ C,
                                               int K, int lda, int ldc) {
    const int tid = threadIdx.x;
    const int lane = tid & 63;
    const int w = tid >> 6;
    const int m0 = blockIdx.y * 128;
    const int n0 = blockIdx.x * 128;
    const int wm = (w >> 1) * 64;
    const int wn = (w & 1) * 64;
    const int ln = lane & 15;
    const int qo = lane >> 4;

    __shared__ bf16 As[128 * 72];
    __shared__ bf16 Bs[128 * 72];

    f32x4 acc[4][4];
#pragma unroll
    for (int mi = 0; mi < 4; ++mi)
#pragma unroll
        for (int ni = 0; ni < 4; ++ni) acc[mi][ni] = f32x4{0.f, 0.f, 0.f, 0.f};

    for (int k0 = 0; k0 < K; k0 += 64) {
#pragma unroll
        for (int i = 0; i < 4; ++i) {
            int v = tid + i * 256;
            int row = v >> 3;
            int col = (v & 7) * 8;
            *(bf16x8*)&As[row * 72 + col] = load8(&A[(size_t)(m0 + row) * lda + k0 + col]);
            *(bf16x8*)&Bs[row * 72 + col] = load8(&B[(size_t)(n0 + row) * K + k0 + col]);
        }
        __syncthreads();
#pragma unroll
        for (int kk = 0; kk < 64; kk += 32) {
            bf16x8 af[4], bfr[4];
#pragma unroll
            for (int mi = 0; mi < 4; ++mi)
                af[mi] = *(const bf16x8*)&As[(wm + mi * 16 + ln) * 72 + kk + qo * 8];
#pragma unroll
            for (int ni = 0; ni < 4; ++ni)
                bfr[ni] = *(const bf16x8*)&Bs[(wn + ni * 16 + ln) * 72 + kk + qo * 8];
#pragma unroll
            for (int mi = 0; mi < 4; ++mi)
#pragma unroll
                for (int ni = 0; ni < 4; ++ni)
                    acc[mi][ni] = mfma16(af[mi], bfr[ni], acc[mi][ni]);
        }
        __syncthreads();
    }
#pragma unroll
    for (int mi = 0; mi < 4; ++mi)
#pragma unroll
        for (int ni = 0; ni < 4; ++ni)
#pragma unroll
            for (int r = 0; r < 4; ++r) {
                int row = m0 + wm + mi * 16 + qo * 4 + r;
                int col = n0 + wn + ni * 16 + ln;
                C[(size_t)row * ldc + col] = (OutT)acc[mi][ni][r];
            }
}

// RoPE in-place on bf16 qkv buffer
__global__ __launch_bounds__(256) void rope_kernel(bf16* __restrict__ qkv,
                                                   const int* __restrict__ positions) {
    int idx = blockIdx.x * 256 + threadIdx.x;
    const int total = S_LEN * (NH + NKV) * 64;
    if (idx >= total) return;
    int d = idx & 63;
    int t = idx >> 6;
    int head = t % (NH + NKV);
    int s = t / (NH + NKV);
    size_t base = (size_t)s * QKV_N + (head < NH ? head * DH : NH * DH + (head - NH) * DH);
    float x1 = (float)qkv[base + d];
    float x2 = (float)qkv[base + d + 64];
    float pos = (float)positions[s];
    float inv = expf(-0.21586735246819178f * (float)d); // 1e6^(-d/64)
    float ang = pos * inv;
    float c = cosf(ang);
    float sn = sinf(ang);
    qkv[base + d] = (bf16)(x1 * c - x2 * sn);
    qkv[base + d + 64] = (bf16)(x2 * c + x1 * sn);
}

// Pre-transpose V into vt_g[kvh][d][s]
__global__ __launch_bounds__(256) void vtrans_kernel(const bf16* __restrict__ qkv,
                                                     bf16* __restrict__ vt_g) {
    const int tid = threadIdx.x;
    const int s0 = blockIdx.x * 64;
    const int kvh = blockIdx.y;
    __shared__ bf16 Ls[64 * 136];
#pragma unroll
    for (int i = 0; i < 4; ++i) {
        int v = tid + i * 256;
        int row = v >> 4;
        int col = (v & 15) * 8;
        *(bf16x8*)&Ls[row * 136 + col] =
            *(const bf16x8*)&qkv[(size_t)(s0 + row) * QKV_N + (NH + NKV) * DH + kvh * DH + col];
    }
    __syncthreads();
#pragma unroll
    for (int i = 0; i < 4; ++i) {
        int u = tid + i * 256;
        int d = u >> 3;
        int sg = (u & 7) * 8;
        bf16x8 r;
#pragma unroll
        for (int j = 0; j < 8; ++j) r[j] = Ls[(sg + j) * 136 + d];
        *(bf16x8*)&vt_g[((size_t)kvh * DH + d) * S_LEN + s0 + sg] = r;
    }
}

// Flash attention (vt_g variant, round-4 proven). O -> Q slot of qkv in-place.
__global__ __launch_bounds__(256) void attn_kernel(bf16* __restrict__ qkv,
                                                   const bf16* __restrict__ vt_g) {
    const int tid = threadIdx.x;
    const int lane = tid & 63;
    const int w = tid >> 6;
    const int ln = lane & 15;
    const int qo = lane >> 4;
    const int qtile = (int)gridDim.x - 1 - (int)blockIdx.x; // heavy first
    const int hq = blockIdx.y;
    const int kvh = hq >> 2;
    const int q0 = qtile * 64;

    __shared__ __align__(16) char smem_raw[2 * 17408 + 18432]; // 53248 B
    bf16* Qs = (bf16*)smem_raw;
    bf16* Ps = (bf16*)smem_raw;               // aliases Qs (dead after frag load)
    bf16* Ks = (bf16*)(smem_raw + 17408);
    bf16* Vt = (bf16*)(smem_raw + 2 * 17408); // 128 x 72 [d][key]

#pragma unroll
    for (int i = 0; i < 4; ++i) {
        int v = tid + i * 256;
        int row = v >> 4;
        int col = (v & 15) * 8;
        *(bf16x8*)&Qs[row * 136 + col] =
            *(const bf16x8*)&qkv[(size_t)(q0 + row) * QKV_N + hq * DH + col];
    }
    __syncthreads();

    bf16x8 aq[4];
#pragma unroll
    for (int ko = 0; ko < 4; ++ko)
        aq[ko] = *(const bf16x8*)&Qs[(w * 16 + ln) * 136 + ko * 32 + qo * 8];

    f32x4 acc[8];
#pragma unroll
    for (int n = 0; n < 8; ++n) acc[n] = f32x4{0.f, 0.f, 0.f, 0.f};
    float m_r[4], l_r[4];
#pragma unroll
    for (int r = 0; r < 4; ++r) { m_r[r] = -1e30f; l_r[r] = 0.f; }

    bf16* Ps_w = &Ps[w * 16 * 72];
    const bf16* vsrc = vt_g + (size_t)kvh * DH * S_LEN;

    for (int kt = 0; kt <= qtile; ++kt) {
        const int k0 = kt * 64;
#pragma unroll
        for (int i = 0; i < 4; ++i) {
            int v = tid + i * 256;
            int row = v >> 4;
            int col = (v & 15) * 8;
            *(bf16x8*)&Ks[row * 136 + col] =
                *(const bf16x8*)&qkv[(size_t)(k0 + row) * QKV_N + NH * DH + kvh * DH + col];
        }
#pragma unroll
        for (int i = 0; i < 4; ++i) {
            int u = tid + i * 256;
            int d = u >> 3;
            int kc = (u & 7) * 8;
            *(bf16x8*)&Vt[d * 72 + kc] =
                *(const bf16x8*)&vsrc[(size_t)d * S_LEN + k0 + kc];
        }
        __syncthreads();

        float p[4][4];
#pragma unroll
        for (int ni = 0; ni < 4; ++ni) {
            f32x4 sacc = f32x4{0.f, 0.f, 0.f, 0.f};
#pragma unroll
            for (int ko = 0; ko < 4; ++ko) {
                bf16x8 bk = *(const bf16x8*)&Ks[(ni * 16 + ln) * 136 + ko * 32 + qo * 8];
                sacc = mfma16(aq[ko], bk, sacc);
            }
#pragma unroll
            for (int r = 0; r < 4; ++r) {
                float val = sacc[r] * SCALE_ATT;
                int qrow = q0 + w * 16 + qo * 4 + r;
                int kcol = k0 + ni * 16 + ln;
                if (kcol > qrow) val = -1e30f;
                p[ni][r] = val;
            }
        }
        float alpha[4];
#pragma unroll
        for (int r = 0; r < 4; ++r) {
            float mx = fmaxf(fmaxf(p[0][r], p[1][r]), fmaxf(p[2][r], p[3][r]));
#pragma unroll
            for (int off = 1; off < 16; off <<= 1)
                mx = fmaxf(mx, __shfl_xor(mx, off, 64));
            float mnew = fmaxf(m_r[r], mx);
            alpha[r] = __expf(m_r[r] - mnew);
            float rs = 0.f;
#pragma unroll
            for (int ni = 0; ni < 4; ++ni) {
                float e = __expf(p[ni][r] - mnew);
                p[ni][r] = e;
                rs += e;
            }
#pragma unroll
            for (int off = 1; off < 16; off <<= 1) rs += __shfl_xor(rs, off, 64);
            l_r[r] = l_r[r] * alpha[r] + rs;
            m_r[r] = mnew;
        }
#pragma unroll
        for (int n = 0; n < 8; ++n)
#pragma unroll
            for (int r = 0; r < 4; ++r) acc[n][r] *= alpha[r];
#pragma unroll
        for (int ni = 0; ni < 4; ++ni)
#pragma unroll
            for (int r = 0; r < 4; ++r)
                Ps_w[(qo * 4 + r) * 72 + ni * 16 + ln] = (bf16)p[ni][r];
        __syncthreads();
#pragma unroll
        for (int ko2 = 0; ko2 < 2; ++ko2) {
            bf16x8 pf = *(const bf16x8*)&Ps_w[ln * 72 + ko2 * 32 + qo * 8];
#pragma unroll
            for (int n = 0; n < 8; ++n) {
                bf16x8 vf = *(const bf16x8*)&Vt[(n * 16 + ln) * 72 + ko2 * 32 + qo * 8];
                acc[n] = mfma16(pf, vf, acc[n]);
            }
        }
        __syncthreads();
    }
#pragma unroll
    for (int r = 0; r < 4; ++r) {
        float invl = 1.f / l_r[r];
        int qrow = q0 + w * 16 + qo * 4 + r;
#pragma unroll
        for (int n = 0; n < 8; ++n)
            qkv[(size_t)qrow * QKV_N + hq * DH + n * 16 + ln] = (bf16)(acc[n][r] * invl);
    }
}

extern "C" void kernel_launch(void* const* d_in, const int* in_sizes, int n_in,
                              void* d_out, int out_size, void* d_ws, size_t ws_size,
                              hipStream_t stream) {
    const int* positions = (const int*)d_in[0];
    const float* hidden = (const float*)d_in[1];
    const float* w_qkv = (const float*)d_in[2];
    const float* w_o = (const float*)d_in[3];
    float* out = (float*)d_out;

    const size_t n_qkv = (size_t)S_LEN * QKV_N;          // 12.58M
    const size_t n_vt = (size_t)NKV * DH * S_LEN;        // 2.10M
    const size_t n_hid = (size_t)S_LEN * HID;            // 8.39M
    const size_t n_wqkv = (size_t)QKV_N * HID;           // 25.17M
    const size_t n_wo = (size_t)HID * HID;               // 16.78M

    const size_t need_min = (n_qkv + n_vt) * sizeof(bf16);                        // 29.4 MB
    const size_t need_full = (n_qkv + n_vt + n_hid + n_wqkv + n_wo) * sizeof(bf16); // 124 MiB
    if (ws_size < need_min) return;

    bf16* qkv = (bf16*)d_ws;
    bf16* vt_g = qkv + n_qkv;
    bf16* hid_b = vt_g + n_vt;
    bf16* wqkv_b = hid_b + n_hid;
    bf16* wo_b = wqkv_b + n_wqkv;
    const bool full = ws_size >= need_full;

    if (full) {
        // 0) fp32 -> bf16 conversions
        cvt_kernel<<<(int)(n_hid / 8 + 255) / 256, 256, 0, stream>>>(hidden, hid_b, (int)(n_hid / 8));
        cvt_kernel<<<(int)(n_wqkv / 8 + 255) / 256, 256, 0, stream>>>(w_qkv, wqkv_b, (int)(n_wqkv / 8));
        cvt_kernel<<<(int)(n_wo / 8 + 255) / 256, 256, 0, stream>>>(w_o, wo_b, (int)(n_wo / 8));
        // 1) qkv = hidden @ w_qkv^T  (swizzled global_load_lds GEMM)
        gemm_bt_swz<<<dim3(QKV_N / 128, S_LEN / 128), 256, 0, stream>>>(hid_b, wqkv_b, qkv, HID, HID, QKV_N);
    } else {
        gemm_bt<<<dim3(QKV_N / 128, S_LEN / 128), 256, 0, stream>>>(hidden, w_qkv, qkv, HID, HID, QKV_N);
    }
    // 2) RoPE
    const int total = S_LEN * (NH + NKV) * 64;
    rope_kernel<<<(total + 255) / 256, 256, 0, stream>>>(qkv, positions);
    // 3) attention
    vtrans_kernel<<<dim3(S_LEN / 64, NKV), 256, 0, stream>>>(qkv, vt_g);
    attn_kernel<<<dim3(S_LEN / 64, NH), 256, 0, stream>>>(qkv, vt_g);
    // 4) out = O @ w_o^T  (A = Q-slot of qkv, lda = 6144)
    if (full) {
        gemm_bt_swz<<<dim3(HID / 128, S_LEN / 128), 256, 0, stream>>>(qkv, wo_b, out, HID, QKV_N, HID);
    } else {
        gemm_bt<<<dim3(HID / 128, S_LEN / 128), 256, 0, stream>>>(qkv, w_o, out, HID, QKV_N, HID);
    }
}